// Round 6
// baseline (8388.295 us; speedup 1.0000x reference)
//
#include <hip/hip_runtime.h>
#include <hip/hip_bf16.h>
#include <stdint.h>

// Problem dims (fixed by reference)
#define B_   16
#define T_   512
#define V_   8192
#define E_   512
#define H_   1024
#define BT_  (B_ * T_)   // 8192 rows, row r = b*T + t
#define H4_  (4 * H_)    // 4096

typedef __attribute__((ext_vector_type(8))) short   short8;
typedef __attribute__((ext_vector_type(8))) __bf16  bf16x8;
typedef __attribute__((ext_vector_type(4))) float   f32x4;
typedef __attribute__((ext_vector_type(4))) short   short4v;
typedef unsigned long long ull;

__device__ __forceinline__ float bf2f(short s) {
  union { unsigned u; float f; } x;
  x.u = ((unsigned)(unsigned short)s) << 16;
  return x.f;
}
__device__ __forceinline__ short f2bf(float f) {
  union { float f; unsigned u; } x; x.f = f;
  unsigned u = x.u;
  u = (u + 0x7fffu + ((u >> 16) & 1u)) >> 16;   // RNE
  return (short)u;
}
__device__ __forceinline__ f32x4 mfma16(short8 a, short8 b, f32x4 c) {
  return __builtin_amdgcn_mfma_f32_16x16x32_bf16(
      __builtin_bit_cast(bf16x8, a), __builtin_bit_cast(bf16x8, b), c, 0, 0, 0);
}
__device__ __forceinline__ float sigm(float x) { return 1.f / (1.f + __expf(-x)); }
__device__ __forceinline__ float tanh_f(float x) { return 1.f - 2.f / (__expf(2.f * x) + 1.f); }

__device__ __forceinline__ short8 mk8(ull lo, ull hi) {
  union { ull u[2]; short8 s; } c;
  c.u[0] = lo; c.u[1] = hi;
  return c.s;
}
// assemble 8 bf16 from the low dwords of 4 epoch-packed ulls
__device__ __forceinline__ short8 pk8(ull a, ull b, ull c, ull d) {
  union { unsigned u[4]; short8 s; } x;
  x.u[0] = (unsigned)a; x.u[1] = (unsigned)b;
  x.u[2] = (unsigned)c; x.u[3] = (unsigned)d;
  return x.s;
}
__device__ __forceinline__ ull packv(short v0, short v1, unsigned ep) {
  return (ull)(unsigned short)v0 | ((ull)(unsigned short)v1 << 16) | ((ull)ep << 32);
}

// async global->LDS, 16B per lane, wave-uniform LDS base + lane*16
__device__ __forceinline__ void gload_lds16(const short* g, short* l) {
  __builtin_amdgcn_global_load_lds(
      (const __attribute__((address_space(1))) unsigned int*)g,
      (__attribute__((address_space(3))) unsigned int*)l, 16, 0, 0);
}

// ---------------------------------------------------------------------------
// 1) column L2-norm scales
__global__ __launch_bounds__(256) void colscale(const float* __restrict__ W,
                                                const float* __restrict__ g,
                                                float* __restrict__ sc, int Kr, int N) {
  int j = blockIdx.x * 256 + threadIdx.x;
  if (j >= N) return;
  float ss = 0.f;
  for (int i = 0; i < Kr; ++i) { float v = W[(long)i * N + j]; ss = fmaf(v, v, ss); }
  sc[j] = g[j] / fmaxf(sqrtf(ss), 1e-12f);
}

// 2) WT[j][i] = bf16(W[i][j] * sc[j]) — LDS 32x32 tile transpose
__global__ __launch_bounds__(256) void transpose_cast(const float* __restrict__ W,
                                                      const float* __restrict__ sc,
                                                      short* __restrict__ WT, int Kr, int N) {
  __shared__ float tile[32][33];
  int nbi = Kr >> 5;
  int bi = blockIdx.x % nbi, bj = blockIdx.x / nbi;
  int i0 = bi << 5, j0 = bj << 5;
  int tx = threadIdx.x & 31, ty = threadIdx.x >> 5;   // 32 x 8
  for (int yy = ty; yy < 32; yy += 8)
    tile[yy][tx] = W[(long)(i0 + yy) * N + j0 + tx];
  __syncthreads();
  for (int yy = ty; yy < 32; yy += 8) {
    int j = j0 + yy;
    WT[(long)j * Kr + i0 + tx] = f2bf(tile[tx][yy] * sc[j]);
  }
}

// 3) plain f32 -> bf16 cast
__global__ __launch_bounds__(256) void castbf(const float* __restrict__ src,
                                              short* __restrict__ dst, long n) {
  long i = ((long)blockIdx.x * 256 + threadIdx.x) * 4;
  if (i + 3 < n) {
    float4 v = *(const float4*)(src + i);
    short4v o = { f2bf(v.x), f2bf(v.y), f2bf(v.z), f2bf(v.w) };
    *(short4v*)(dst + i) = o;
  }
}

// 4) embedding gather with padding_idx=0 -> zeros
__global__ __launch_bounds__(256) void embed_gather(const int* __restrict__ xs,
                                                    const float* __restrict__ ew,
                                                    short* __restrict__ x) {
  int r = blockIdx.x;
  int idx = xs[r];
  const float* src = ew + (long)idx * E_;
  for (int e = threadIdx.x; e < E_; e += 256) {
    float v = (idx == 0) ? 0.f : src[e];
    x[(long)r * E_ + e] = f2bf(v);
  }
}

// ---------------------------------------------------------------------------
// Generic 128x128-tile bf16 MFMA GEMM: C[M][N](bf16) = A[M][K] @ BT[N][K]^T (+bias)
__global__ __launch_bounds__(256) void gemm_bt(const short* __restrict__ A,
                                               const short* __restrict__ BT,
                                               const float* __restrict__ bias,
                                               short* __restrict__ C,
                                               int M, int N, int K) {
  int ntiles = N >> 7;
  int tM = (blockIdx.x / ntiles) << 7;
  int tN = (blockIdx.x % ntiles) << 7;
  int w = threadIdx.x >> 6, lane = threadIdx.x & 63;
  int mo = tM + ((w & 1) << 6), no = tN + ((w >> 1) << 6);
  int lr = lane & 15, lk8 = (lane >> 4) << 3, q = lane >> 4;
  f32x4 acc[4][4] = {};
  const short* Ap = A + (long)(mo + lr) * K + lk8;
  const short* Bp = BT + (long)(no + lr) * K + lk8;
  for (int k0 = 0; k0 < K; k0 += 32) {
    short8 af[4], bfr[4];
#pragma unroll
    for (int i = 0; i < 4; ++i) af[i] = *(const short8*)(Ap + (long)16 * i * K + k0);
#pragma unroll
    for (int j = 0; j < 4; ++j) bfr[j] = *(const short8*)(Bp + (long)16 * j * K + k0);
#pragma unroll
    for (int i = 0; i < 4; ++i)
#pragma unroll
      for (int j = 0; j < 4; ++j)
        acc[i][j] = mfma16(af[i], bfr[j], acc[i][j]);
  }
  float pbv[4];
#pragma unroll
  for (int j = 0; j < 4; ++j) pbv[j] = bias ? bias[no + 16 * j + lr] : 0.f;
#pragma unroll
  for (int i = 0; i < 4; ++i)
#pragma unroll
    for (int j = 0; j < 4; ++j)
#pragma unroll
      for (int r = 0; r < 4; ++r) {
        int row = mo + 16 * i + 4 * q + r;      // C/D layout: row = quad*4+reg
        int col = no + 16 * j + lr;             //             col = lane&15
        C[(long)row * N + col] = f2bf(acc[i][j][r] + pbv[j]);
      }
}

// ---------------------------------------------------------------------------
// Logits GEMM, m97-style LDS-staged (global_load_lds width16, BK=32, 128x128),
// with fused exp-sum + target-logit capture epilogue.
__global__ __launch_bounds__(256) void gemm_logits(const short* __restrict__ A,
                                                   const short* __restrict__ BT,
                                                   const float* __restrict__ pb,
                                                   const int* __restrict__ ys,
                                                   float* __restrict__ sumexp,
                                                   float* __restrict__ logit_y,
                                                   int M, int N, int K) {
  __shared__ short As[128 * 32];   // [row][32] bf16, 8 KB
  __shared__ short Bs[128 * 32];   // [col][32] bf16, 8 KB
  int ntiles = N >> 7;
  int tM = (blockIdx.x / ntiles) << 7;
  int tN = (blockIdx.x % ntiles) << 7;
  int w = threadIdx.x >> 6, lane = threadIdx.x & 63;
  int mo = (w & 1) << 6, no = (w >> 1) << 6;          // local quadrant offsets
  int lr = lane & 15, q = lane >> 4;
  int sr = lane >> 2, sk = (lane & 3) << 3;           // staging: row-in-16, k-offset
  f32x4 acc[4][4] = {};

  const short* Ag = A + (long)(tM + 32 * w + sr) * K + sk;
  const short* Bg = BT + (long)(tN + 32 * w + sr) * K + sk;
  short* Al0 = As + (32 * w) * 32;
  short* Al1 = As + (32 * w + 16) * 32;
  short* Bl0 = Bs + (32 * w) * 32;
  short* Bl1 = Bs + (32 * w + 16) * 32;

  for (int k0 = 0; k0 < K; k0 += 32) {
    gload_lds16(Ag + k0, Al0);
    gload_lds16(Ag + k0 + (long)16 * K, Al1);
    gload_lds16(Bg + k0, Bl0);
    gload_lds16(Bg + k0 + (long)16 * K, Bl1);
    __syncthreads();                                   // drains vmcnt before barrier
    short8 af[4], bfr[4];
#pragma unroll
    for (int i = 0; i < 4; ++i) af[i] = *(const short8*)(As + (mo + 16 * i + lr) * 32 + q * 8);
#pragma unroll
    for (int j = 0; j < 4; ++j) bfr[j] = *(const short8*)(Bs + (no + 16 * j + lr) * 32 + q * 8);
#pragma unroll
    for (int i = 0; i < 4; ++i)
#pragma unroll
      for (int j = 0; j < 4; ++j)
        acc[i][j] = mfma16(af[i], bfr[j], acc[i][j]);
    __syncthreads();
  }

  int moG = tM + mo, noG = tN + no;
  float pbv[4];
#pragma unroll
  for (int j = 0; j < 4; ++j) pbv[j] = pb[noG + 16 * j + lr];
#pragma unroll
  for (int i = 0; i < 4; ++i) {
#pragma unroll
    for (int r = 0; r < 4; ++r) {
      int row = moG + 16 * i + 4 * q + r;
      int ysr = ys[row];
      float s = 0.f;
#pragma unroll
      for (int j = 0; j < 4; ++j) {
        float v = acc[i][j][r] + pbv[j];
        s += __expf(v);
        int col = noG + 16 * j + lr;
        if (col == ysr) logit_y[row] = v;
      }
      s += __shfl_xor(s, 1); s += __shfl_xor(s, 2);
      s += __shfl_xor(s, 4); s += __shfl_xor(s, 8);
      if (lr == 0) atomicAdd(&sumexp[row], s);
    }
  }
}

// ---------------------------------------------------------------------------
// Persistent recurrent scan. 64 WGs x 256 threads. Exchange via EPOCH-PACKED
// 8-byte words ([bf16 v0 | bf16 v1 | epoch32]) stored with relaxed agent-scope
// atomics: no flags, no store-ack waits — consumers poll directly on the data,
// so detect and data arrival are the same LIC round-trip.
#define NWG_ 64

__global__ __launch_bounds__(256, 1) void scan_kernel(
    const short* __restrict__ zxb, const short* __restrict__ mxb,
    const short* __restrict__ wmhT, const short* __restrict__ whT,
    short* __restrict__ hs,
    ull* __restrict__ h_pack,       // [16][512] epoch-packed pairs, memset 0
    ull* __restrict__ m_pack) {     // [16][512] epoch-packed pairs, memset 0
  const int g = blockIdx.x;
  const int tid = threadIdx.x;
  const int w = tid >> 6, lane = tid & 63;
  const int lr = lane & 15, q = lane >> 4;
  const int colg = g << 4;
  const int b = tid >> 4, cl = tid & 15;

  __shared__ float red1[4][16][16];          //  4 KB
  __shared__ float red2[4][4][16][16];       // 16 KB
  __shared__ __align__(8) short mtile[16][16];
  __shared__ __align__(8) short htile[16][16];

  // ---- preload weights into registers (atomic loads: not rematerializable) ----
  short8 wmh_f[8];   // phase1 B: col colg+lr, k = w*256 + kk*32 + q*8
#pragma unroll
  for (int kk = 0; kk < 8; ++kk) {
    const ull* p = (const ull*)(wmhT + (long)(colg + lr) * H_ + (w << 8) + (kk << 5) + (q << 3));
    ull lo = __hip_atomic_load(p, __ATOMIC_RELAXED, __HIP_MEMORY_SCOPE_WORKGROUP);
    ull hi = __hip_atomic_load(p + 1, __ATOMIC_RELAXED, __HIP_MEMORY_SCOPE_WORKGROUP);
    wmh_f[kk] = mk8(lo, hi);
  }
  short8 wh_f[4][8]; // phase2 B: col gate*H + colg + lr, same k-slice
#pragma unroll
  for (int gt = 0; gt < 4; ++gt)
#pragma unroll
    for (int kk = 0; kk < 8; ++kk) {
      const ull* p = (const ull*)(whT + (long)(gt * H_ + colg + lr) * H_ + (w << 8) + (kk << 5) + (q << 3));
      ull lo = __hip_atomic_load(p, __ATOMIC_RELAXED, __HIP_MEMORY_SCOPE_WORKGROUP);
      ull hi = __hip_atomic_load(p + 1, __ATOMIC_RELAXED, __HIP_MEMORY_SCOPE_WORKGROUP);
      wh_f[gt][kk] = mk8(lo, hi);
    }

  float c = 0.f;
  // consumer bases: row lr, k-slice w*256 + q*8 (pair index = k/2)
  const ull* hb = h_pack + lr * 512 + (w << 7) + (q << 2);
  const ull* mb = m_pack + lr * 512 + (w << 7) + (q << 2);
  // producer indices (tid<128): b2 = tid>>3 row, j = tid&7 pair within 16 cols
  const int pb2 = tid >> 3, pj = tid & 7;
  ull* mst = m_pack + pb2 * 512 + (colg >> 1) + pj;
  ull* hst = h_pack + pb2 * 512 + (colg >> 1) + pj;

  for (int t = 0; t < T_; ++t) {
    // prefetch this step's zx/mx (plain cached loads; overlap the polls)
    long rrow = (long)(b * T_ + t);
    short mx_p = mxb[rrow * H_ + colg + cl];
    const short* zrow = zxb + rrow * H4_ + colg + cl;
    short z0p = zrow[0 * H_], z1p = zrow[1 * H_], z2p = zrow[2 * H_], z3p = zrow[3 * H_];

    // ---- phase 1: poll h(t) by epoch, m = mx_t * (h @ wmh) ----
    ull hv[32];
    {
      const unsigned et = (unsigned)t;
      for (;;) {
        unsigned bad = 0;
#pragma unroll
        for (int kk = 0; kk < 8; ++kk)
#pragma unroll
          for (int u = 0; u < 4; ++u)
            hv[kk * 4 + u] = __hip_atomic_load(hb + (kk << 4) + u,
                                               __ATOMIC_RELAXED, __HIP_MEMORY_SCOPE_AGENT);
#pragma unroll
        for (int i = 0; i < 32; ++i) bad |= ((unsigned)(hv[i] >> 32)) ^ et;
        if (__all(bad == 0)) break;
      }
    }
    f32x4 a1 = {};
#pragma unroll
    for (int kk = 0; kk < 8; ++kk)
      a1 = mfma16(pk8(hv[4 * kk], hv[4 * kk + 1], hv[4 * kk + 2], hv[4 * kk + 3]),
                  wmh_f[kk], a1);
#pragma unroll
    for (int r = 0; r < 4; ++r) red1[w][q * 4 + r][lr] = a1[r];
    __syncthreads();
    {
      float hw = red1[0][b][cl] + red1[1][b][cl] + red1[2][b][cl] + red1[3][b][cl];
      mtile[b][cl] = f2bf(bf2f(mx_p) * hw);
    }
    __syncthreads();
    if (tid < 128) {
      ull v = packv(mtile[pb2][2 * pj], mtile[pb2][2 * pj + 1], (unsigned)(t + 1));
      __hip_atomic_store(mst, v, __ATOMIC_RELAXED, __HIP_MEMORY_SCOPE_AGENT);
    }

    // ---- phase 2: poll m(t) by epoch, z = zx + m @ wh (k-split), gates ----
    ull lm[32];
    {
      const unsigned et = (unsigned)(t + 1);
      for (;;) {
        unsigned bad = 0;
#pragma unroll
        for (int kk = 0; kk < 8; ++kk)
#pragma unroll
          for (int u = 0; u < 4; ++u)
            lm[kk * 4 + u] = __hip_atomic_load(mb + (kk << 4) + u,
                                               __ATOMIC_RELAXED, __HIP_MEMORY_SCOPE_AGENT);
#pragma unroll
        for (int i = 0; i < 32; ++i) bad |= ((unsigned)(lm[i] >> 32)) ^ et;
        if (__all(bad == 0)) break;
      }
    }
    f32x4 a2[4] = {};
#pragma unroll
    for (int kk = 0; kk < 8; ++kk) {
      short8 mf = pk8(lm[4 * kk], lm[4 * kk + 1], lm[4 * kk + 2], lm[4 * kk + 3]);
#pragma unroll
      for (int gt = 0; gt < 4; ++gt)
        a2[gt] = mfma16(mf, wh_f[gt][kk], a2[gt]);
    }
#pragma unroll
    for (int gt = 0; gt < 4; ++gt)
#pragma unroll
      for (int r = 0; r < 4; ++r)
        red2[w][gt][q * 4 + r][lr] = a2[gt][r];
    __syncthreads();
    {
      float zi = red2[0][0][b][cl] + red2[1][0][b][cl] + red2[2][0][b][cl] + red2[3][0][b][cl] + bf2f(z0p);
      float zf = red2[0][1][b][cl] + red2[1][1][b][cl] + red2[2][1][b][cl] + red2[3][1][b][cl] + bf2f(z1p);
      float zo = red2[0][2][b][cl] + red2[1][2][b][cl] + red2[2][2][b][cl] + red2[3][2][b][cl] + bf2f(z2p);
      float zu = red2[0][3][b][cl] + red2[1][3][b][cl] + red2[2][3][b][cl] + red2[3][3][b][cl] + bf2f(z3p);
      float ig = sigm(zi), fg = sigm(zf), og = sigm(zo), ug = tanh_f(zu);
      c = fg * c + ig * ug;
      float h = og * tanh_f(c);
      short hb16 = f2bf(h);
      htile[b][cl] = hb16;
      hs[rrow * H_ + colg + cl] = hb16;   // plain store; consumed after kernel end
    }
    __syncthreads();
    if (tid < 128) {
      ull v = packv(htile[pb2][2 * pj], htile[pb2][2 * pj + 1], (unsigned)(t + 1));
      __hip_atomic_store(hst, v, __ATOMIC_RELAXED, __HIP_MEMORY_SCOPE_AGENT);
    }
  }
}

// ---------------------------------------------------------------------------
__global__ __launch_bounds__(256) void reduce_nll(const float* __restrict__ se,
                                                  const float* __restrict__ ly,
                                                  float* __restrict__ out) {
  __shared__ float buf[256];
  float s = 0.f;
  for (int r = threadIdx.x; r < BT_; r += 256)
    s += logf(se[r]) - ly[r];
  buf[threadIdx.x] = s;
  __syncthreads();
  for (int off = 128; off > 0; off >>= 1) {
    if (threadIdx.x < off) buf[threadIdx.x] += buf[threadIdx.x + off];
    __syncthreads();
  }
  if (threadIdx.x == 0) out[0] = buf[0] * (1.0f / BT_);
}

// ---------------------------------------------------------------------------
extern "C" void kernel_launch(void* const* d_in, const int* in_sizes, int n_in,
                              void* d_out, int out_size, void* d_ws, size_t ws_size,
                              hipStream_t stream) {
  const int*   xs     = (const int*)d_in[0];
  const int*   ys     = (const int*)d_in[1];
  const float* embw   = (const float*)d_in[2];
  const float* wx     = (const float*)d_in[3];
  const float* wh     = (const float*)d_in[4];
  const float* wmx    = (const float*)d_in[5];
  const float* wmh    = (const float*)d_in[6];
  const float* bias   = (const float*)d_in[7];
  const float* gx     = (const float*)d_in[8];
  const float* gh     = (const float*)d_in[9];
  const float* gmx    = (const float*)d_in[10];
  const float* gmh    = (const float*)d_in[11];
  const float* pred_w = (const float*)d_in[12];
  const float* pred_b = (const float*)d_in[13];
  float* out = (float*)d_out;

  char* base = (char*)d_ws;
  size_t off = 0;
  auto alloc = [&](size_t bytes) -> void* {
    void* p = base + off;
    off = (off + bytes + 255) & ~(size_t)255;
    return p;
  };
  short* xb     = (short*)alloc((size_t)BT_ * E_ * 2);   //  8 MB
  short* zxb    = (short*)alloc((size_t)BT_ * H4_ * 2);  // 64 MB
  short* mxb    = (short*)alloc((size_t)BT_ * H_ * 2);   // 16 MB
  short* hs     = (short*)alloc((size_t)BT_ * H_ * 2);   // 16 MB
  short* wxT    = (short*)alloc((size_t)H4_ * E_ * 2);   //  4 MB
  short* whT    = (short*)alloc((size_t)H4_ * H_ * 2);   //  8 MB
  short* wmxT   = (short*)alloc((size_t)H_ * E_ * 2);    //  1 MB
  short* wmhT   = (short*)alloc((size_t)H_ * H_ * 2);    //  2 MB
  short* pwb    = (short*)alloc((size_t)V_ * H_ * 2);    // 16 MB
  float* scx    = (float*)alloc(H4_ * 4);
  float* sch    = (float*)alloc(H4_ * 4);
  float* scmx   = (float*)alloc(H_ * 4);
  float* scmh   = (float*)alloc(H_ * 4);
  float* l_y    = (float*)alloc(BT_ * 4);
  // ---- zero zone (one memset covers all of these) ----
  size_t z0 = off;
  float* sumexp = (float*)alloc(BT_ * 4);                // 32 KB
  ull*   h_pack = (ull*)alloc((size_t)B_ * 512 * 8);     // 64 KB (epoch 0 = init)
  ull*   m_pack = (ull*)alloc((size_t)B_ * 512 * 8);     // 64 KB
  size_t zlen = off - z0;

  hipMemsetAsync(base + z0, 0, zlen, stream);

  // weight norm -> transposed bf16 copies
  colscale<<<H4_ / 256, 256, 0, stream>>>(wx, gx, scx, E_, H4_);
  colscale<<<H4_ / 256, 256, 0, stream>>>(wh, gh, sch, H_, H4_);
  colscale<<<H_ / 256, 256, 0, stream>>>(wmx, gmx, scmx, E_, H_);
  colscale<<<H_ / 256, 256, 0, stream>>>(wmh, gmh, scmh, H_, H_);
  transpose_cast<<<(E_ / 32) * (H4_ / 32), 256, 0, stream>>>(wx, scx, wxT, E_, H4_);
  transpose_cast<<<(H_ / 32) * (H4_ / 32), 256, 0, stream>>>(wh, sch, whT, H_, H4_);
  transpose_cast<<<(E_ / 32) * (H_ / 32), 256, 0, stream>>>(wmx, scmx, wmxT, E_, H_);
  transpose_cast<<<(H_ / 32) * (H_ / 32), 256, 0, stream>>>(wmh, scmh, wmhT, H_, H_);
  castbf<<<((long)V_ * H_) / 1024, 256, 0, stream>>>(pred_w, pwb, (long)V_ * H_);

  // embed + input-dependent projections
  embed_gather<<<BT_, 256, 0, stream>>>(xs, embw, xb);
  gemm_bt<<<(BT_ / 128) * (H4_ / 128), 256, 0, stream>>>(xb, wxT, bias, zxb, BT_, H4_, E_);
  gemm_bt<<<(BT_ / 128) * (H_ / 128), 256, 0, stream>>>(xb, wmxT, nullptr, mxb, BT_, H_, E_);

  // sequential mLSTM scan (persistent, epoch-packed single-RT exchange)
  scan_kernel<<<NWG_, 256, 0, stream>>>(zxb, mxb, wmhT, whT, hs, h_pack, m_pack);

  // fused logits (LDS-staged) + exp-sum + target logit, then mean NLL
  gemm_logits<<<(BT_ / 128) * (V_ / 128), 256, 0, stream>>>(hs, pwb, pred_b, ys,
                                                            sumexp, l_y, BT_, V_, H_);
  reduce_nll<<<1, 256, 0, stream>>>(sumexp, l_y, out);
}